// Round 5
// baseline (249.666 us; speedup 1.0000x reference)
//
#include <hip/hip_runtime.h>
#include <cstdint>
#include <cstddef>

#define B    8
#define SEQ  2048
#define H    4
#define DKN  5
#define DIM  20
#define PRE8 8
#define PSTR32 68             // LDS P-tile row stride in dwords (272B): writes 2/bank, reads balanced
#define SENTB ((short)0xC6E0) // bf16(-28672): exp2(x-28672) == 0
#define ONEB  ((short)0x3F80) // bf16(1.0)

typedef short short8 __attribute__((ext_vector_type(8)));
typedef float f32x4 __attribute__((ext_vector_type(4)));

#if __has_builtin(__builtin_amdgcn_exp2f)
#define EXP2(x) __builtin_amdgcn_exp2f(x)
#else
#define EXP2(x) __expf((x) * 0.6931471805599453f)
#endif

static __device__ __forceinline__ unsigned short bf16b(float x) {
    union { float f; unsigned u; } v; v.f = x;
    unsigned r = v.u + 0x7FFFu + ((v.u >> 16) & 1u);   // RTNE
    return (unsigned short)(r >> 16);
}
static __device__ __forceinline__ float bf16f(unsigned short h) {
    union { unsigned u; float f; } v; v.u = ((unsigned)h) << 16;
    return v.f;
}
// packed bf16 pair: low short = a, high short = b
static __device__ __forceinline__ unsigned pk_bf16(float a, float b) {
#if __has_builtin(__builtin_amdgcn_cvt_pk_bf16_f32)
    auto t = __builtin_amdgcn_cvt_pk_bf16_f32(a, b);
    unsigned u; __builtin_memcpy(&u, &t, 4);
    return u;
#else
    return (unsigned)bf16b(a) | ((unsigned)bf16b(b) << 16);
#endif
}
// key s (within 128-block) -> permuted column position (inverse of P pk-interleave)
static __device__ __forceinline__ int sigma128(int t) {
    return (t & 96) | (((t & 15) << 1) | ((t >> 4) & 1));
}

// ws layout (shorts unless noted):
//   Qt : [x][b][h][s][16]   hi(0..7: q*QSC bf16-hi, [5]=1) | lo(8..15: residual, [5]=0)
//   Kt : [x][b][h][s][8]    compacted keys by position; positions >= cnt sentinel ([5]=-28672)
//   Vt : [x][b][h][8][SEQ]  transposed values at sigma-permuted columns; row5 = 1 (l-col)
//   pre: float [p][b][h][s][PRE8]
//   idx/meta: int

// ---------------- compaction only ----------------
__global__ __launch_bounds__(64) void compact_kernel(
    const int* __restrict__ mask, int* __restrict__ idx, int* __restrict__ meta)
{
    int b = blockIdx.x, lane = threadIdx.x;
    const int* m = mask + b * SEQ;
    int* out = idx + b * SEQ;
    int base = 0;
    for (int c = 0; c < SEQ; c += 64) {
        int v = m[c + lane];
        unsigned long long bal = __ballot(v != 0);
        int pre = __popcll(bal & ((1ull << lane) - 1ull));
        if (v) out[base + pre] = c + lane;
        base += (int)__popcll(bal);
    }
    if (lane == 0) meta[b] = base;
}

// ---------------- projections (one (x,b,h,s) per thread) ----------------
__global__ __launch_bounds__(256) void proj_kernel(
    const float* __restrict__ q, const float* __restrict__ k, const float* __restrict__ v,
    const float* __restrict__ W0, const float* __restrict__ b0,
    const float* __restrict__ W1, const float* __restrict__ b1,
    const float* __restrict__ W2, const float* __restrict__ b2,
    const int* __restrict__ idx, const int* __restrict__ meta,
    short* __restrict__ Qt, short* __restrict__ Kt, short* __restrict__ Vt)
{
    __shared__ float Ws[3][DIM * DIM];
    __shared__ float bsh[3][DIM];
    int tid = threadIdx.x;
    for (int i = tid; i < DIM * DIM; i += 256) {
        Ws[0][i] = W0[i]; Ws[1][i] = W1[i]; Ws[2][i] = W2[i];
    }
    if (tid < DIM) { bsh[0][tid] = b0[tid]; bsh[1][tid] = b1[tid]; bsh[2][tid] = b2[tid]; }
    __syncthreads();

    int g   = blockIdx.x * 256 + tid;     // 3*B*H*SEQ = 196608 exactly
    int s   = g & (SEQ - 1);  g >>= 11;
    int h   = g & (H - 1);    g >>= 2;
    int bb  = g & (B - 1);    g >>= 3;
    int x   = g;                          // 0..2

    const float QSC = 0.44721359549995793f * 1.4426950408889634f;  // (1/sqrt5)*log2(e)
    const float* base = (x == 0) ? q : ((x == 1) ? k : v);

    float xq[DIM];
    {
        const float* xr = base + (size_t)(bb * SEQ + s) * DIM;
        #pragma unroll
        for (int i = 0; i < DIM; ++i) xq[i] = xr[i];
    }
    int  cnt   = meta[bb];
    bool valid = s < cnt;
    int  gs    = valid ? idx[bb * SEQ + s] : 0;
    float xg[DIM];
    {
        const float* xr = base + (size_t)(bb * SEQ + gs) * DIM;
        #pragma unroll
        for (int i = 0; i < DIM; ++i) xg[i] = xr[i];
    }

    #define DOT20(xv, t, j, dst) {                                        \
        float acc_ = bsh[t][j];                                           \
        const float4* wr_ = (const float4*)&Ws[t][(j) * DIM];             \
        _Pragma("unroll")                                                 \
        for (int i4 = 0; i4 < 5; ++i4) {                                  \
            float4 w_ = wr_[i4];                                          \
            acc_ += (xv)[i4*4+0]*w_.x + (xv)[i4*4+1]*w_.y                 \
                  + (xv)[i4*4+2]*w_.z + (xv)[i4*4+3]*w_.w;                \
        }                                                                 \
        dst = acc_;                                                       \
    }

    size_t row = ((size_t)(x * B + bb) * H + h) * SEQ + s;

    // Q-role (W0): pre-scaled, hi/lo bf16 split; hi[5]=1 (bias), lo[5]=0
    short8 qhi = {0, 0, 0, 0, 0, ONEB, 0, 0};
    short8 qlo = {0, 0, 0, 0, 0, 0, 0, 0};
    #pragma unroll
    for (int d = 0; d < DKN; ++d) {
        float y; DOT20(xq, 0, h * DKN + d, y);
        y *= QSC;
        unsigned short hb = bf16b(y);
        qhi[d] = (short)hb;
        qlo[d] = (short)bf16b(y - bf16f(hb));
    }
    ((short8*)Qt)[row * 2 + 0] = qhi;
    ((short8*)Qt)[row * 2 + 1] = qlo;

    // K-role (W1): real key or sentinel ([5] = -28672 -> P = 0)
    short8 rk = {0, 0, 0, 0, 0, valid ? (short)0 : SENTB, 0, 0};
    if (valid) {
        #pragma unroll
        for (int d = 0; d < DKN; ++d) {
            float y; DOT20(xg, 1, h * DKN + d, y);
            rk[d] = (short)bf16b(y);
        }
    }
    ((short8*)Kt)[row] = rk;

    // V-role (W2): transposed store at sigma-permuted column; row5 = 1
    if (valid) {
        size_t vb = ((size_t)(x * B + bb) * H + h) * 8 * SEQ;
        int vcol = (s & ~127) + sigma128(s & 127);
        #pragma unroll
        for (int d = 0; d < DKN; ++d) {
            float y; DOT20(xg, 2, h * DKN + d, y);
            Vt[vb + (size_t)d * SEQ + vcol] = (short)bf16b(y);
        }
        Vt[vb + (size_t)5 * SEQ + vcol] = ONEB;
    }
}

// ---------------- MFMA flash attention (bf16, 128-key iterations) ----------------
__global__ __launch_bounds__(256) void attn_kernel(
    const short* __restrict__ Qt, const short* __restrict__ Kt,
    const short* __restrict__ Vt, const int* __restrict__ meta,
    float* __restrict__ pre)
{
    __shared__ unsigned Ptile[4][16 * PSTR32];   // per-wave 16 q-rows x 128 keys (bf16 pairs)

    int tid  = threadIdx.x;
    int wave = tid >> 6, lane = tid & 63;
    int col  = lane & 15, quad = lane >> 4;

    int lin = blockIdx.x;          // 6*8*4*32 = 6144
    int qt  = lin & 31; lin >>= 5;
    int h   = lin & 3;  lin >>= 2;
    int b   = lin & 7;  lin >>= 3;
    int p   = lin;
    int a   = (0x212010 >> (4 * p)) & 0xF;   // Q source
    int kv  = (0x120201 >> (4 * p)) & 0xF;   // K/V source

    const short*  Qb = Qt + ((size_t)(a  * B + b) * H + h) * SEQ * 16;
    const short8* Kb = (const short8*)Kt + ((size_t)(kv * B + b) * H + h) * SEQ;
    const short*  Vb = Vt + ((size_t)(kv * B + b) * H + h) * 8 * SEQ;

    int cnt  = meta[b];
    int kend = (cnt + 127) & ~127;

    int qbase = qt * 64 + wave * 16;
    // A-frag: A[m=col][k=quad*8+j]; quad0 = Q-hi (k 0..7), quad1 = Q-lo (k 8..15)
    short8 qf = {0, 0, 0, 0, 0, 0, 0, 0};
    if (quad < 2) qf = *(const short8*)(Qb + (size_t)(qbase + col) * 16 + quad * 8);

    unsigned* Pl = Ptile[wave];
    f32x4 acc = {0.f, 0.f, 0.f, 0.f};
    f32x4 zc  = {0.f, 0.f, 0.f, 0.f};
    int vrow = col & 7;   // Vt rows 0..7; acc cols 8..15 unused duplicates

    for (int c0 = 0; c0 < kend; c0 += 128) {
        // K-frags for 8 chunks of 16 keys (quad>=2 lanes: A is zero there, value irrelevant)
        short8 kf0={0,0,0,0,0,0,0,0}, kf1=kf0, kf2=kf0, kf3=kf0, kf4=kf0, kf5=kf0, kf6=kf0, kf7=kf0;
        if (quad < 2) {
            const short8* Kc = Kb + c0;
            kf0 = Kc[col];      kf1 = Kc[16 + col];
            kf2 = Kc[32 + col]; kf3 = Kc[48 + col];
            kf4 = Kc[64 + col]; kf5 = Kc[80 + col];
            kf6 = Kc[96 + col]; kf7 = Kc[112 + col];
        }
        // V-frags (issued early; consumed after second barrier)
        const short* Vr = Vb + (size_t)vrow * SEQ + c0 + quad * 8;
        short8 vf0 = *(const short8*)(Vr);
        short8 vf1 = *(const short8*)(Vr + 32);
        short8 vf2 = *(const short8*)(Vr + 64);
        short8 vf3 = *(const short8*)(Vr + 96);

        f32x4 s0 = __builtin_amdgcn_mfma_f32_16x16x32_bf16(qf, kf0, zc, 0, 0, 0);
        f32x4 s1 = __builtin_amdgcn_mfma_f32_16x16x32_bf16(qf, kf1, zc, 0, 0, 0);
        f32x4 s2 = __builtin_amdgcn_mfma_f32_16x16x32_bf16(qf, kf2, zc, 0, 0, 0);
        f32x4 s3 = __builtin_amdgcn_mfma_f32_16x16x32_bf16(qf, kf3, zc, 0, 0, 0);

        __syncthreads();   // WAR: previous iteration's P reads complete
        // C-layout: col=key-within-16, row=quad*4+r. Pack chunk pairs (2i,2i+1)
        int wb = (quad * 4) * PSTR32 + col;
        #pragma unroll
        for (int r = 0; r < 4; ++r) {
            Pl[wb + r * PSTR32     ] = pk_bf16(EXP2(s0[r]), EXP2(s1[r]));
            Pl[wb + r * PSTR32 + 16] = pk_bf16(EXP2(s2[r]), EXP2(s3[r]));
        }
        f32x4 s4 = __builtin_amdgcn_mfma_f32_16x16x32_bf16(qf, kf4, zc, 0, 0, 0);
        f32x4 s5 = __builtin_amdgcn_mfma_f32_16x16x32_bf16(qf, kf5, zc, 0, 0, 0);
        f32x4 s6 = __builtin_amdgcn_mfma_f32_16x16x32_bf16(qf, kf6, zc, 0, 0, 0);
        f32x4 s7 = __builtin_amdgcn_mfma_f32_16x16x32_bf16(qf, kf7, zc, 0, 0, 0);
        #pragma unroll
        for (int r = 0; r < 4; ++r) {
            Pl[wb + r * PSTR32 + 32] = pk_bf16(EXP2(s4[r]), EXP2(s5[r]));
            Pl[wb + r * PSTR32 + 48] = pk_bf16(EXP2(s6[r]), EXP2(s7[r]));
        }
        __syncthreads();   // make P visible

        // A-frag: P[m=q=col][k=position quad*8+j] per 32-position group m
        const unsigned* Pr = Pl + col * PSTR32 + quad * 4;
        short8 pf0 = *(const short8*)(Pr);
        short8 pf1 = *(const short8*)(Pr + 16);
        short8 pf2 = *(const short8*)(Pr + 32);
        short8 pf3 = *(const short8*)(Pr + 48);

        acc = __builtin_amdgcn_mfma_f32_16x16x32_bf16(pf0, vf0, acc, 0, 0, 0);
        acc = __builtin_amdgcn_mfma_f32_16x16x32_bf16(pf1, vf1, acc, 0, 0, 0);
        acc = __builtin_amdgcn_mfma_f32_16x16x32_bf16(pf2, vf2, acc, 0, 0, 0);
        acc = __builtin_amdgcn_mfma_f32_16x16x32_bf16(pf3, vf3, acc, 0, 0, 0);
    }

    // C-layout: col = n (vdim; n==5 is l), row = quad*4+r (q within 16)
    float* prow = pre + (((size_t)p * B + b) * H + h) * SEQ * PRE8 + (size_t)qbase * PRE8;
    #pragma unroll
    for (int r = 0; r < 4; ++r) {
        float lv = __shfl(acc[r], (lane & 48) | 5, 64);
        float ov = acc[r] / lv;
        if (col < DKN) prow[(quad * 4 + r) * PRE8 + col] = ov;
    }
}

// ---------------- sum 6 pairs + output projection ----------------
__global__ __launch_bounds__(256) void final_kernel(
    const float* __restrict__ pre,
    const float* __restrict__ W3, const float* __restrict__ b3,
    float* __restrict__ out)
{
    __shared__ float Ws[DIM * DIM];
    __shared__ float bs[DIM];
    int tid = threadIdx.x;
    for (int i = tid; i < DIM * DIM; i += 256) Ws[i] = W3[i];
    if (tid < DIM) bs[tid] = b3[tid];
    __syncthreads();

    int g = blockIdx.x * 256 + tid;      // B*SEQ = 16384 exactly
    int b = g / SEQ;
    int s = g - b * SEQ;

    float x[DIM];
    #pragma unroll
    for (int i = 0; i < DIM; ++i) x[i] = 0.f;

    for (int p = 0; p < 6; ++p) {
        #pragma unroll
        for (int h = 0; h < H; ++h) {
            const float* sr = pre + (((size_t)p * B + b) * H + h) * SEQ * PRE8
                                  + (size_t)s * PRE8;
            float4 a = *(const float4*)sr;
            float  a4 = sr[4];
            x[h * DKN + 0] += a.x; x[h * DKN + 1] += a.y; x[h * DKN + 2] += a.z;
            x[h * DKN + 3] += a.w; x[h * DKN + 4] += a4;
        }
    }

    float y[DIM];
    for (int j = 0; j < DIM; ++j) {
        float acc = bs[j];
        const float4* wr = (const float4*)&Ws[j * DIM];
        #pragma unroll
        for (int i4 = 0; i4 < 5; ++i4) {
            float4 w = wr[i4];
            acc += x[i4*4+0]*w.x + x[i4*4+1]*w.y + x[i4*4+2]*w.z + x[i4*4+3]*w.w;
        }
        y[j] = acc;
    }
    float4* dst = (float4*)(out + (size_t)(b * SEQ + s) * DIM);
    #pragma unroll
    for (int j4 = 0; j4 < 5; ++j4)
        dst[j4] = make_float4(y[j4*4+0], y[j4*4+1], y[j4*4+2], y[j4*4+3]);
}

extern "C" void kernel_launch(void* const* d_in, const int* in_sizes, int n_in,
                              void* d_out, int out_size, void* d_ws, size_t ws_size,
                              hipStream_t stream) {
    const float* q    = (const float*)d_in[0];
    const float* k    = (const float*)d_in[1];
    const float* v    = (const float*)d_in[2];
    const int*   mask = (const int*)d_in[3];
    const float* W0 = (const float*)d_in[4];  const float* b0 = (const float*)d_in[5];
    const float* W1 = (const float*)d_in[6];  const float* b1 = (const float*)d_in[7];
    const float* W2 = (const float*)d_in[8];  const float* b2 = (const float*)d_in[9];
    const float* W3 = (const float*)d_in[10]; const float* b3 = (const float*)d_in[11];

    short* Qt = (short*)d_ws;                                // 3*B*H*SEQ*16 shorts (6 MB)
    short* Kt = Qt + (size_t)3 * B * H * SEQ * 16;           // 3*B*H*SEQ*8  shorts (3 MB)
    short* Vt = Kt + (size_t)3 * B * H * SEQ * 8;            // 3*B*H*8*SEQ  shorts (3 MB)
    float* pre = (float*)(Vt + (size_t)3 * B * H * 8 * SEQ); // 6*B*H*SEQ*8 floats (12.6 MB)
    int*   idx = (int*)(pre + (size_t)6 * B * H * SEQ * PRE8);
    int*   meta = idx + (size_t)B * SEQ;
    float* out = (float*)d_out;

    compact_kernel<<<dim3(B), dim3(64), 0, stream>>>(mask, idx, meta);
    proj_kernel<<<dim3(3 * B * H * SEQ / 256), dim3(256), 0, stream>>>(
        q, k, v, W0, b0, W1, b1, W2, b2, idx, meta, Qt, Kt, Vt);
    attn_kernel<<<dim3(6 * B * H * 32), dim3(256), 0, stream>>>(Qt, Kt, Vt, meta, pre);
    final_kernel<<<dim3(B * SEQ / 256), dim3(256), 0, stream>>>(pre, W3, b3, out);
}

// Round 7
// 248.487 us; speedup vs baseline: 1.0047x; 1.0047x over previous
//
#include <hip/hip_runtime.h>
#include <cstdint>
#include <cstddef>

#define B    8
#define SEQ  2048
#define H    4
#define DKN  5
#define DIM  20
#define PRE8 8
#define SENTB ((short)0xC6E0) // bf16(-28672): exp2(x-28672) == 0
#define ONEB  ((short)0x3F80) // bf16(1.0)

typedef short short8 __attribute__((ext_vector_type(8)));
typedef unsigned u32x4 __attribute__((ext_vector_type(4)));
typedef float f32x4 __attribute__((ext_vector_type(4)));

#if __has_builtin(__builtin_amdgcn_exp2f)
#define EXP2(x) __builtin_amdgcn_exp2f(x)
#else
#define EXP2(x) __expf((x) * 0.6931471805599453f)
#endif

static __device__ __forceinline__ unsigned short bf16b(float x) {
    union { float f; unsigned u; } v; v.f = x;
    unsigned r = v.u + 0x7FFFu + ((v.u >> 16) & 1u);   // RTNE
    return (unsigned short)(r >> 16);
}
static __device__ __forceinline__ float bf16f(unsigned short h) {
    union { unsigned u; float f; } v; v.u = ((unsigned)h) << 16;
    return v.f;
}
static __device__ __forceinline__ unsigned pk_bf16(float a, float b) {
#if __has_builtin(__builtin_amdgcn_cvt_pk_bf16_f32)
    auto t = __builtin_amdgcn_cvt_pk_bf16_f32(a, b);
    unsigned u; __builtin_memcpy(&u, &t, 4);
    return u;
#else
    return (unsigned)bf16b(a) | ((unsigned)bf16b(b) << 16);
#endif
}
// key k (0..31) -> Vt column slot matching the lane-local P fragment order
// (PV B-frag slot t holds key 16*((t>>2)&1) + 4*(t>>3) + (t&3); this is the inverse)
static __device__ __forceinline__ int sig32(int k) {
    return (((k >> 2) & 3) << 3) + (((k >> 4) & 1) << 2) + (k & 3);
}

// ws layout (R5-proven, no aliasing):
//   Qt : short [x][b][h][s][16]   hi(0..7, [5]=1 bias) | lo(8..15, [5]=0)   6 MB
//   Kt : short [x][b][h][c][8]    compacted keys; c>=cnt sentinel           3 MB
//   Vt : short [x][b][h][8][SEQ]  transposed values at sig32 columns; r5=1  3 MB
//   pre: float [p][b][h][s][8]                                             12.6 MB
//   idx/meta: int

// ---------------- compaction ----------------
__global__ __launch_bounds__(64) void compact_kernel(
    const int* __restrict__ mask, int* __restrict__ idx, int* __restrict__ meta)
{
    int b = blockIdx.x, lane = threadIdx.x;
    const int* m = mask + b * SEQ;
    int* out = idx + b * SEQ;
    int base = 0;
    for (int c = 0; c < SEQ; c += 64) {
        int v = m[c + lane];
        unsigned long long bal = __ballot(v != 0);
        int pre = __popcll(bal & ((1ull << lane) - 1ull));
        if (v) out[base + pre] = c + lane;
        base += (int)__popcll(bal);
    }
    if (lane == 0) meta[b] = base;
}

// ---------------- projections (one (x,b,h,s) per thread; gather-in-proj) ----------------
__global__ __launch_bounds__(256) void proj_kernel(
    const float* __restrict__ q, const float* __restrict__ k, const float* __restrict__ v,
    const float* __restrict__ W0, const float* __restrict__ b0,
    const float* __restrict__ W1, const float* __restrict__ b1,
    const float* __restrict__ W2, const float* __restrict__ b2,
    const int* __restrict__ idx, const int* __restrict__ meta,
    short* __restrict__ Qt, short* __restrict__ Kt, short* __restrict__ Vt)
{
    __shared__ float Ws[3][DIM * DIM];
    __shared__ float bsh[3][DIM];
    int tid = threadIdx.x;
    for (int i = tid; i < DIM * DIM; i += 256) {
        Ws[0][i] = W0[i]; Ws[1][i] = W1[i]; Ws[2][i] = W2[i];
    }
    if (tid < DIM) { bsh[0][tid] = b0[tid]; bsh[1][tid] = b1[tid]; bsh[2][tid] = b2[tid]; }
    __syncthreads();

    int g   = blockIdx.x * 256 + tid;     // 3*B*H*SEQ = 196608 exactly
    int s   = g & (SEQ - 1);  g >>= 11;
    int h   = g & (H - 1);    g >>= 2;
    int bb  = g & (B - 1);    g >>= 3;
    int x   = g;                          // 0..2

    const float QSC = 0.44721359549995793f * 1.4426950408889634f;  // (1/sqrt5)*log2(e)
    const float* base = (x == 0) ? q : ((x == 1) ? k : v);

    float xq[DIM];
    {
        const float* xr = base + (size_t)(bb * SEQ + s) * DIM;
        #pragma unroll
        for (int i = 0; i < DIM; ++i) xq[i] = xr[i];
    }
    int  cnt   = meta[bb];
    bool valid = s < cnt;
    int  gs    = valid ? idx[bb * SEQ + s] : 0;
    float xg[DIM];
    {
        const float* xr = base + (size_t)(bb * SEQ + gs) * DIM;
        #pragma unroll
        for (int i = 0; i < DIM; ++i) xg[i] = xr[i];
    }

    #define DOT20(xv, t, j, dst) {                                        \
        float acc_ = bsh[t][j];                                           \
        const float4* wr_ = (const float4*)&Ws[t][(j) * DIM];             \
        _Pragma("unroll")                                                 \
        for (int i4 = 0; i4 < 5; ++i4) {                                  \
            float4 w_ = wr_[i4];                                          \
            acc_ += (xv)[i4*4+0]*w_.x + (xv)[i4*4+1]*w_.y                 \
                  + (xv)[i4*4+2]*w_.z + (xv)[i4*4+3]*w_.w;                \
        }                                                                 \
        dst = acc_;                                                       \
    }

    size_t row = ((size_t)(x * B + bb) * H + h) * SEQ + s;

    // Q-role (W0): pre-scaled, hi/lo bf16 split; hi[5]=1 (bias), lo[5]=0
    short8 qhi = {0, 0, 0, 0, 0, ONEB, 0, 0};
    short8 qlo = {0, 0, 0, 0, 0, 0, 0, 0};
    #pragma unroll
    for (int d = 0; d < DKN; ++d) {
        float y; DOT20(xq, 0, h * DKN + d, y);
        y *= QSC;
        unsigned short hb = bf16b(y);
        qhi[d] = (short)hb;
        qlo[d] = (short)bf16b(y - bf16f(hb));
    }
    ((short8*)Qt)[row * 2 + 0] = qhi;
    ((short8*)Qt)[row * 2 + 1] = qlo;

    // K-role (W1) on gathered key row, or sentinel ([5] = -28672 -> P = 0)
    short8 rk = {0, 0, 0, 0, 0, valid ? (short)0 : SENTB, 0, 0};
    if (valid) {
        #pragma unroll
        for (int d = 0; d < DKN; ++d) {
            float y; DOT20(xg, 1, h * DKN + d, y);
            rk[d] = (short)bf16b(y);
        }
    }
    ((short8*)Kt)[row] = rk;

    // V-role (W2): transposed store at sig32-permuted column; row5 = 1 (l-col)
    if (valid) {
        size_t vb = ((size_t)(x * B + bb) * H + h) * 8 * SEQ;
        int vcol = (s & ~31) + sig32(s & 31);
        #pragma unroll
        for (int d = 0; d < DKN; ++d) {
            float y; DOT20(xg, 2, h * DKN + d, y);
            Vt[vb + (size_t)d * SEQ + vcol] = (short)bf16b(y);
        }
        Vt[vb + (size_t)5 * SEQ + vcol] = ONEB;
        // Vt columns >= cnt / rows 6-7 left as-is: P there is exactly 0, and
        // acc rows 6-7 are never stored (harness-poison values are finite).
    }
}

// ---------------- barrier-free MFMA flash attention (S^T form) ----------------
__global__ __launch_bounds__(256) void attn_kernel(
    const short* __restrict__ Qt, const short* __restrict__ Kt,
    const short* __restrict__ Vt, const int* __restrict__ meta,
    float* __restrict__ pre)
{
    int tid  = threadIdx.x;
    int wave = tid >> 6, lane = tid & 63;
    int col  = lane & 15, quad = lane >> 4;

    int lin = blockIdx.x;          // 6*8*4*32 = 6144
    int qt  = lin & 31; lin >>= 5;
    int h   = lin & 3;  lin >>= 2;
    int b   = lin & 7;  lin >>= 3;
    int p   = lin;
    int a   = (0x212010 >> (4 * p)) & 0xF;   // Q source
    int kv  = (0x120201 >> (4 * p)) & 0xF;   // K/V source

    const short*  Qb = Qt + ((size_t)(a  * B + b) * H + h) * SEQ * 16;
    const short8* Kb = (const short8*)Kt + ((size_t)(kv * B + b) * H + h) * SEQ;
    const short*  Vb = Vt + ((size_t)(kv * B + b) * H + h) * 8 * SEQ;

    int cnt  = meta[b];
    int kend = (cnt + 31) & ~31;

    int qbase = qt * 64 + wave * 16;
    // B-frag Q: B[n=q=col][k=quad*8+j]; quad0=Q-hi, quad1=Q-lo, quads 2,3 ZERO
    // (zeros also nullify K garbage at k=16..31 of the A-frag).
    short8 qf = {0, 0, 0, 0, 0, 0, 0, 0};
    if (quad < 2) qf = *(const short8*)(Qb + (size_t)(qbase + col) * 16 + quad * 8);

    f32x4 acc = {0.f, 0.f, 0.f, 0.f};
    f32x4 zc  = {0.f, 0.f, 0.f, 0.f};
    const short* Vr0 = Vb + (size_t)(col & 7) * SEQ + quad * 8;

    #pragma unroll 2
    for (int c0 = 0; c0 < kend; c0 += 32) {
        // A-frag K: A[m=key=col][k]; all quads load (k>=16 killed by qf zeros)
        short8 kf0 = Kb[c0 + col];
        short8 kf1 = Kb[c0 + 16 + col];
        // A-frag V^T: A[m=d=col&7][k=key slot quad*8+j] (sig32-permuted columns)
        short8 vf  = *(const short8*)(Vr0 + c0);

        // S^T: D[m=key][n=q]; lane(col=q) holds keys quad*4+r (s0) and 16+quad*4+r (s1)
        f32x4 s0 = __builtin_amdgcn_mfma_f32_16x16x32_bf16(kf0, qf, zc, 0, 0, 0);
        f32x4 s1 = __builtin_amdgcn_mfma_f32_16x16x32_bf16(kf1, qf, zc, 0, 0, 0);

        // exp2 -> packed bf16: this lane's own 8 P values ARE its PV B-frag
        u32x4 pd;
        pd[0] = pk_bf16(EXP2(s0[0]), EXP2(s0[1]));
        pd[1] = pk_bf16(EXP2(s0[2]), EXP2(s0[3]));
        pd[2] = pk_bf16(EXP2(s1[0]), EXP2(s1[1]));
        pd[3] = pk_bf16(EXP2(s1[2]), EXP2(s1[3]));
        short8 pf;
        __builtin_memcpy(&pf, &pd, 16);

        // O^T: D[m=d][n=q]; row5 = softmax denominator (Vt row5 = 1)
        acc = __builtin_amdgcn_mfma_f32_16x16x32_bf16(vf, pf, acc, 0, 0, 0);
    }

    // l for q=col lives at lane (quad=1, col), reg 1 (row 5 = 1*4+1)
    float lv  = __shfl(acc[1], 16 + col, 64);
    float inv = 1.0f / lv;
    float* dst = pre + (((size_t)p * B + b) * H + h) * SEQ * PRE8
                     + (size_t)(qbase + col) * PRE8;
    if (quad == 0) {
        *(float4*)dst = make_float4(acc[0] * inv, acc[1] * inv, acc[2] * inv, acc[3] * inv);
    } else if (quad == 1) {
        dst[4] = acc[0] * inv;    // d=4 (row 4 = 1*4+0)
    }
}

// ---------------- sum 6 pairs + output projection ----------------
__global__ __launch_bounds__(256) void final_kernel(
    const float* __restrict__ pre,
    const float* __restrict__ W3, const float* __restrict__ b3,
    float* __restrict__ out)
{
    __shared__ float Ws[DIM * DIM];
    __shared__ float bs[DIM];
    int tid = threadIdx.x;
    for (int i = tid; i < DIM * DIM; i += 256) Ws[i] = W3[i];
    if (tid < DIM) bs[tid] = b3[tid];
    __syncthreads();

    int g = blockIdx.x * 256 + tid;      // B*SEQ = 16384 exactly
    int b = g / SEQ;
    int s = g - b * SEQ;

    float x[DIM];
    #pragma unroll
    for (int i = 0; i < DIM; ++i) x[i] = 0.f;

    for (int p = 0; p < 6; ++p) {
        #pragma unroll
        for (int h = 0; h < H; ++h) {
            const float* sr = pre + (((size_t)p * B + b) * H + h) * SEQ * PRE8
                                  + (size_t)s * PRE8;
            float4 a = *(const float4*)sr;
            float  a4 = sr[4];
            x[h * DKN + 0] += a.x; x[h * DKN + 1] += a.y; x[h * DKN + 2] += a.z;
            x[h * DKN + 3] += a.w; x[h * DKN + 4] += a4;
        }
    }

    float y[DIM];
    for (int j = 0; j < DIM; ++j) {
        float acc = bs[j];
        const float4* wr = (const float4*)&Ws[j * DIM];
        #pragma unroll
        for (int i4 = 0; i4 < 5; ++i4) {
            float4 w = wr[i4];
            acc += x[i4*4+0]*w.x + x[i4*4+1]*w.y + x[i4*4+2]*w.z + x[i4*4+3]*w.w;
        }
        y[j] = acc;
    }
    float4* dst = (float4*)(out + (size_t)(b * SEQ + s) * DIM);
    #pragma unroll
    for (int j4 = 0; j4 < 5; ++j4)
        dst[j4] = make_float4(y[j4*4+0], y[j4*4+1], y[j4*4+2], y[j4*4+3]);
}

extern "C" void kernel_launch(void* const* d_in, const int* in_sizes, int n_in,
                              void* d_out, int out_size, void* d_ws, size_t ws_size,
                              hipStream_t stream) {
    const float* q    = (const float*)d_in[0];
    const float* k    = (const float*)d_in[1];
    const float* v    = (const float*)d_in[2];
    const int*   mask = (const int*)d_in[3];
    const float* W0 = (const float*)d_in[4];  const float* b0 = (const float*)d_in[5];
    const float* W1 = (const float*)d_in[6];  const float* b1 = (const float*)d_in[7];
    const float* W2 = (const float*)d_in[8];  const float* b2 = (const float*)d_in[9];
    const float* W3 = (const float*)d_in[10]; const float* b3 = (const float*)d_in[11];

    const size_t NROW = (size_t)3 * B * H * SEQ;       // 196608
    short* Qt = (short*)d_ws;                          // NROW*16 shorts (6 MB)
    short* Kt = Qt + NROW * 16;                        // NROW*8 shorts  (3 MB)
    short* Vt = Kt + NROW * 8;                         // NROW*8 shorts  (3 MB)
    float* pre = (float*)(Vt + NROW * 8);              // 6*B*H*SEQ*8 floats (12.6 MB)
    int*   idx  = (int*)(pre + (size_t)6 * B * H * SEQ * PRE8);
    int*   meta = idx + (size_t)B * SEQ;
    float* out  = (float*)d_out;

    compact_kernel<<<dim3(B), dim3(64), 0, stream>>>(mask, idx, meta);
    proj_kernel<<<dim3(3 * B * H * SEQ / 256), dim3(256), 0, stream>>>(
        q, k, v, W0, b0, W1, b1, W2, b2, idx, meta, Qt, Kt, Vt);
    attn_kernel<<<dim3(6 * B * H * 32), dim3(256), 0, stream>>>(Qt, Kt, Vt, meta, pre);
    final_kernel<<<dim3(B * SEQ / 256), dim3(256), 0, stream>>>(pre, W3, b3, out);
}

// Round 8
// 220.580 us; speedup vs baseline: 1.1319x; 1.1265x over previous
//
#include <hip/hip_runtime.h>
#include <cstdint>
#include <cstddef>

#define B    8
#define SEQ  2048
#define H    4
#define DKN  5
#define DIM  20
#define PRE8 8
#define SENTB ((short)0xC6E0) // bf16(-28672): exp2(x-28672) == 0
#define ONEB  ((short)0x3F80) // bf16(1.0)

typedef short short8 __attribute__((ext_vector_type(8)));
typedef float f32x16 __attribute__((ext_vector_type(16)));

#if __has_builtin(__builtin_amdgcn_exp2f)
#define EXP2(x) __builtin_amdgcn_exp2f(x)
#else
#define EXP2(x) __expf((x) * 0.6931471805599453f)
#endif

static __device__ __forceinline__ unsigned short bf16b(float x) {
    union { float f; unsigned u; } v; v.f = x;
    unsigned r = v.u + 0x7FFFu + ((v.u >> 16) & 1u);   // RTNE
    return (unsigned short)(r >> 16);
}
static __device__ __forceinline__ float bf16f(unsigned short h) {
    union { unsigned u; float f; } v; v.u = ((unsigned)h) << 16;
    return v.f;
}
// one-instruction truncating bf16 pack: D = {hi16(y), hi16(x)} via v_perm_b32
static __device__ __forceinline__ unsigned pk_trunc(float x, float y) {
    union { float f; unsigned u; } a, b; a.f = x; b.f = y;
    return __builtin_amdgcn_perm(b.u, a.u, 0x07060302u);
}
// key offset t (0..31) -> Vt physical column slot for the 32x32x16 PV pipeline:
// PV B-frag k-slot s must hold key sigma(s); this is the inverse map (store side).
static __device__ __forceinline__ int sig32(int t) {
    return (t & 19) | ((t & 4) << 1) | ((t & 8) >> 1);
}

// ws layout:
//   Qt : short [x][b][h][s][16]   hi(0..7, [5]=1 bias) | lo(8..15, [5]=0)   6 MB
//   Kt : short [x][b][h][c][8]    compacted keys; c>=cnt sentinel           3 MB
//   Vt : short [x][b][h][8][SEQ]  transposed values at sig32 columns; r5=1  3 MB
//   pre: float [p][b][h][s][8]                                             12.6 MB
//   idx/meta: int

// ---------------- compaction ----------------
__global__ __launch_bounds__(64) void compact_kernel(
    const int* __restrict__ mask, int* __restrict__ idx, int* __restrict__ meta)
{
    int b = blockIdx.x, lane = threadIdx.x;
    const int* m = mask + b * SEQ;
    int* out = idx + b * SEQ;
    int base = 0;
    for (int c = 0; c < SEQ; c += 64) {
        int v = m[c + lane];
        unsigned long long bal = __ballot(v != 0);
        int pre = __popcll(bal & ((1ull << lane) - 1ull));
        if (v) out[base + pre] = c + lane;
        base += (int)__popcll(bal);
    }
    if (lane == 0) meta[b] = base;
}

// ---------------- projections (one (x,b,h,s) per thread; gather-in-proj) ----------------
__global__ __launch_bounds__(256) void proj_kernel(
    const float* __restrict__ q, const float* __restrict__ k, const float* __restrict__ v,
    const float* __restrict__ W0, const float* __restrict__ b0,
    const float* __restrict__ W1, const float* __restrict__ b1,
    const float* __restrict__ W2, const float* __restrict__ b2,
    const int* __restrict__ idx, const int* __restrict__ meta,
    short* __restrict__ Qt, short* __restrict__ Kt, short* __restrict__ Vt)
{
    __shared__ float Ws[3][DIM * DIM];
    __shared__ float bsh[3][DIM];
    int tid = threadIdx.x;
    for (int i = tid; i < DIM * DIM; i += 256) {
        Ws[0][i] = W0[i]; Ws[1][i] = W1[i]; Ws[2][i] = W2[i];
    }
    if (tid < DIM) { bsh[0][tid] = b0[tid]; bsh[1][tid] = b1[tid]; bsh[2][tid] = b2[tid]; }
    __syncthreads();

    int g   = blockIdx.x * 256 + tid;     // 3*B*H*SEQ = 196608 exactly
    int s   = g & (SEQ - 1);  g >>= 11;
    int h   = g & (H - 1);    g >>= 2;
    int bb  = g & (B - 1);    g >>= 3;
    int x   = g;                          // 0..2

    const float QSC = 0.44721359549995793f * 1.4426950408889634f;  // (1/sqrt5)*log2(e)
    const float* base = (x == 0) ? q : ((x == 1) ? k : v);

    float xq[DIM];
    {
        const float* xr = base + (size_t)(bb * SEQ + s) * DIM;
        #pragma unroll
        for (int i = 0; i < DIM; ++i) xq[i] = xr[i];
    }
    int  cnt   = meta[bb];
    bool valid = s < cnt;
    int  gs    = valid ? idx[bb * SEQ + s] : 0;
    float xg[DIM];
    {
        const float* xr = base + (size_t)(bb * SEQ + gs) * DIM;
        #pragma unroll
        for (int i = 0; i < DIM; ++i) xg[i] = xr[i];
    }

    #define DOT20(xv, t, j, dst) {                                        \
        float acc_ = bsh[t][j];                                           \
        const float4* wr_ = (const float4*)&Ws[t][(j) * DIM];             \
        _Pragma("unroll")                                                 \
        for (int i4 = 0; i4 < 5; ++i4) {                                  \
            float4 w_ = wr_[i4];                                          \
            acc_ += (xv)[i4*4+0]*w_.x + (xv)[i4*4+1]*w_.y                 \
                  + (xv)[i4*4+2]*w_.z + (xv)[i4*4+3]*w_.w;                \
        }                                                                 \
        dst = acc_;                                                       \
    }

    size_t row = ((size_t)(x * B + bb) * H + h) * SEQ + s;

    // Q-role (W0): pre-scaled, hi/lo bf16 split; hi[5]=1 (bias), lo[5]=0
    short8 qhi = {0, 0, 0, 0, 0, ONEB, 0, 0};
    short8 qlo = {0, 0, 0, 0, 0, 0, 0, 0};
    #pragma unroll
    for (int d = 0; d < DKN; ++d) {
        float y; DOT20(xq, 0, h * DKN + d, y);
        y *= QSC;
        unsigned short hb = bf16b(y);
        qhi[d] = (short)hb;
        qlo[d] = (short)bf16b(y - bf16f(hb));
    }
    ((short8*)Qt)[row * 2 + 0] = qhi;
    ((short8*)Qt)[row * 2 + 1] = qlo;

    // K-role (W1) on gathered key row, or sentinel ([5] = -28672 -> P = 0)
    short8 rk = {0, 0, 0, 0, 0, valid ? (short)0 : SENTB, 0, 0};
    if (valid) {
        #pragma unroll
        for (int d = 0; d < DKN; ++d) {
            float y; DOT20(xg, 1, h * DKN + d, y);
            rk[d] = (short)bf16b(y);
        }
    }
    ((short8*)Kt)[row] = rk;

    // V-role (W2): transposed store at sig32-permuted column; row5 = 1 (l-col)
    if (valid) {
        size_t vb = ((size_t)(x * B + bb) * H + h) * 8 * SEQ;
        int vcol = (s & ~31) + sig32(s & 31);
        #pragma unroll
        for (int d = 0; d < DKN; ++d) {
            float y; DOT20(xg, 2, h * DKN + d, y);
            Vt[vb + (size_t)d * SEQ + vcol] = (short)bf16b(y);
        }
        Vt[vb + (size_t)5 * SEQ + vcol] = ONEB;
    }
}

// ---------------- barrier-free MFMA flash attention (32x32x16 S^T form) ----------------
__global__ __launch_bounds__(256) void attn_kernel(
    const short* __restrict__ Qt, const short* __restrict__ Kt,
    const short* __restrict__ Vt, const int* __restrict__ meta,
    float* __restrict__ pre)
{
    int tid  = threadIdx.x;
    int wave = tid >> 6, lane = tid & 63;
    int l31  = lane & 31, half = lane >> 5;

    int lin = blockIdx.x;          // 6*8*4*16 = 3072
    int qt  = lin & 15; lin >>= 4;
    int h   = lin & 3;  lin >>= 2;
    int b   = lin & 7;  lin >>= 3;
    int p   = lin;
    int a   = (0x212010 >> (4 * p)) & 0xF;   // Q source
    int kv  = (0x120201 >> (4 * p)) & 0xF;   // K/V source

    const short*  Qb = Qt + ((size_t)(a  * B + b) * H + h) * SEQ * 16;
    const short8* Kb = (const short8*)Kt + ((size_t)(kv * B + b) * H + h) * SEQ;
    const short*  Vb = Vt + ((size_t)(kv * B + b) * H + h) * 8 * SEQ;

    int cnt  = meta[b];
    int kend = (cnt + 31) & ~31;
    int iters = kend >> 5;

    int qbase = qt * 128 + wave * 32;
    // B-frag Q (32x32x16): B[n=q=l31][k=half*8+j]; half0 = Q-hi (k0-7), half1 = Q-lo (k8-15)
    short8 qf = *(const short8*)(Qb + (size_t)(qbase + l31) * 16 + half * 8);

    f32x16 acc = {0.f,0.f,0.f,0.f,0.f,0.f,0.f,0.f,0.f,0.f,0.f,0.f,0.f,0.f,0.f,0.f};
    f32x16 zc  = acc;
    const short* Vr = Vb + (size_t)(l31 & 7) * SEQ + half * 8;

    // prefetch iteration 0
    short8 kf = Kb[l31];
    short8 va = *(const short8*)(Vr);
    short8 vc = *(const short8*)(Vr + 16);

    for (int it = 0; it < iters; ++it) {
        int c1 = (it + 1) << 5;
        // prefetch next iteration (last one reads stray in-ws bytes, never consumed)
        short8 kf_n = Kb[c1 + l31];
        short8 va_n = *(const short8*)(Vr + c1);
        short8 vc_n = *(const short8*)(Vr + c1 + 16);

        // S^T: A=K[m=key=l31][k=half*8+j] (same row both halves = hi/lo contract),
        //      B=Q. D: col=q=l31, key=(reg&3)+8*(reg>>2)+4*half
        f32x16 d = __builtin_amdgcn_mfma_f32_32x32x16_bf16(kf, qf, zc, 0, 0, 0);

        // exp2 -> trunc bf16 pairs; D-reg order == PV B-frag k-slot order (sig32'd V)
        unsigned pd1[4], pd2[4];
        #pragma unroll
        for (int r = 0; r < 4; ++r) {
            pd1[r] = pk_trunc(EXP2(d[2 * r]),     EXP2(d[2 * r + 1]));
            pd2[r] = pk_trunc(EXP2(d[2 * r + 8]), EXP2(d[2 * r + 9]));
        }
        short8 pf1, pf2;
        __builtin_memcpy(&pf1, pd1, 16);
        __builtin_memcpy(&pf2, pd2, 16);

        // O^T: A=V^T[m=dim][k-slot], B=P[n=q][k-slot]; Vt row5=1 -> row5 of D = l
        acc = __builtin_amdgcn_mfma_f32_32x32x16_bf16(va, pf1, acc, 0, 0, 0);
        acc = __builtin_amdgcn_mfma_f32_32x32x16_bf16(vc, pf2, acc, 0, 0, 0);

        kf = kf_n; va = va_n; vc = vc_n;
    }

    // D rows: dim0-3 = half0 regs 0-3; dim4 = half1 reg0; l (row5) = half1 reg1
    float lv  = __shfl(acc[1], 32 + l31, 64);
    float inv = 1.0f / lv;
    float* dst = pre + (((size_t)p * B + b) * H + h) * SEQ * PRE8
                     + (size_t)(qbase + l31) * PRE8;
    if (half == 0) {
        *(float4*)dst = make_float4(acc[0] * inv, acc[1] * inv, acc[2] * inv, acc[3] * inv);
    } else {
        dst[4] = acc[0] * inv;
    }
}

// ---------------- sum 6 pairs + output projection ----------------
__global__ __launch_bounds__(256) void final_kernel(
    const float* __restrict__ pre,
    const float* __restrict__ W3, const float* __restrict__ b3,
    float* __restrict__ out)
{
    __shared__ float Ws[DIM * DIM];
    __shared__ float bs[DIM];
    int tid = threadIdx.x;
    for (int i = tid; i < DIM * DIM; i += 256) Ws[i] = W3[i];
    if (tid < DIM) bs[tid] = b3[tid];
    __syncthreads();

    int g = blockIdx.x * 256 + tid;      // B*SEQ = 16384 exactly
    int b = g / SEQ;
    int s = g - b * SEQ;

    float x[DIM];
    #pragma unroll
    for (int i = 0; i < DIM; ++i) x[i] = 0.f;

    for (int p = 0; p < 6; ++p) {
        #pragma unroll
        for (int h = 0; h < H; ++h) {
            const float* sr = pre + (((size_t)p * B + b) * H + h) * SEQ * PRE8
                                  + (size_t)s * PRE8;
            float4 a = *(const float4*)sr;
            float  a4 = sr[4];
            x[h * DKN + 0] += a.x; x[h * DKN + 1] += a.y; x[h * DKN + 2] += a.z;
            x[h * DKN + 3] += a.w; x[h * DKN + 4] += a4;
        }
    }

    float y[DIM];
    for (int j = 0; j < DIM; ++j) {
        float acc = bs[j];
        const float4* wr = (const float4*)&Ws[j * DIM];
        #pragma unroll
        for (int i4 = 0; i4 < 5; ++i4) {
            float4 w = wr[i4];
            acc += x[i4*4+0]*w.x + x[i4*4+1]*w.y + x[i4*4+2]*w.z + x[i4*4+3]*w.w;
        }
        y[j] = acc;
    }
    float4* dst = (float4*)(out + (size_t)(b * SEQ + s) * DIM);
    #pragma unroll
    for (int j4 = 0; j4 < 5; ++j4)
        dst[j4] = make_float4(y[j4*4+0], y[j4*4+1], y[j4*4+2], y[j4*4+3]);
}

extern "C" void kernel_launch(void* const* d_in, const int* in_sizes, int n_in,
                              void* d_out, int out_size, void* d_ws, size_t ws_size,
                              hipStream_t stream) {
    const float* q    = (const float*)d_in[0];
    const float* k    = (const float*)d_in[1];
    const float* v    = (const float*)d_in[2];
    const int*   mask = (const int*)d_in[3];
    const float* W0 = (const float*)d_in[4];  const float* b0 = (const float*)d_in[5];
    const float* W1 = (const float*)d_in[6];  const float* b1 = (const float*)d_in[7];
    const float* W2 = (const float*)d_in[8];  const float* b2 = (const float*)d_in[9];
    const float* W3 = (const float*)d_in[10]; const float* b3 = (const float*)d_in[11];

    const size_t NROW = (size_t)3 * B * H * SEQ;       // 196608
    short* Qt = (short*)d_ws;                          // NROW*16 shorts (6 MB)
    short* Kt = Qt + NROW * 16;                        // NROW*8 shorts  (3 MB)
    short* Vt = Kt + NROW * 8;                         // NROW*8 shorts  (3 MB)
    float* pre = (float*)(Vt + NROW * 8);              // 6*B*H*SEQ*8 floats (12.6 MB)
    int*   idx  = (int*)(pre + (size_t)6 * B * H * SEQ * PRE8);
    int*   meta = idx + (size_t)B * SEQ;
    float* out  = (float*)d_out;

    compact_kernel<<<dim3(B), dim3(64), 0, stream>>>(mask, idx, meta);
    proj_kernel<<<dim3(3 * B * H * SEQ / 256), dim3(256), 0, stream>>>(
        q, k, v, W0, b0, W1, b1, W2, b2, idx, meta, Qt, Kt, Vt);
    attn_kernel<<<dim3(6 * B * H * 16), dim3(256), 0, stream>>>(Qt, Kt, Vt, meta, pre);
    final_kernel<<<dim3(B * SEQ / 256), dim3(256), 0, stream>>>(pre, W3, b3, out);
}

// Round 9
// 206.724 us; speedup vs baseline: 1.2077x; 1.0670x over previous
//
#include <hip/hip_runtime.h>
#include <cstdint>
#include <cstddef>

#define B    8
#define SEQ  2048
#define H    4
#define DKN  5
#define DIM  20
#define PRE8 8
#define SENTB ((short)0xC6E0) // bf16(-28672): exp2(score-28672) == 0
#define ONEB  ((short)0x3F80) // bf16(1.0)

typedef short short8 __attribute__((ext_vector_type(8)));
typedef float f32x16 __attribute__((ext_vector_type(16)));

#if __has_builtin(__builtin_amdgcn_exp2f)
#define EXP2(x) __builtin_amdgcn_exp2f(x)
#else
#define EXP2(x) __expf((x) * 0.6931471805599453f)
#endif

static __device__ __forceinline__ unsigned short bf16b(float x) {
    union { float f; unsigned u; } v; v.f = x;
    unsigned r = v.u + 0x7FFFu + ((v.u >> 16) & 1u);   // RTNE
    return (unsigned short)(r >> 16);
}
static __device__ __forceinline__ float bf16f(unsigned short h) {
    union { unsigned u; float f; } v; v.u = ((unsigned)h) << 16;
    return v.f;
}
// one-instruction truncating bf16 pack: D = {hi16(y), hi16(x)} via v_perm_b32
static __device__ __forceinline__ unsigned pk_trunc(float x, float y) {
    union { float f; unsigned u; } a, b; a.f = x; b.f = y;
    return __builtin_amdgcn_perm(b.u, a.u, 0x07060302u);
}
// key offset t (0..31) -> Vt physical column slot (32x32x16 PV k-slot inverse)
static __device__ __forceinline__ int sig32(int t) {
    return (t & 19) | ((t & 4) << 1) | ((t & 8) >> 1);
}

// ws layout:
//   Qt : short [x][b][h][s][16]   hi(0..7, [5]=1 bias) | lo(8..15, [5]=0)   6 MB
//   Kt : short [x][b][h][c][8]    compacted keys; c>=cnt sentinel           3 MB
//   Vt : short [x][b][h][8][SEQ]  transposed values at sig32 columns; r5=1  3 MB
//   pre: float [p][b][h][s][8]                                             12.6 MB

// ---------------- projections + in-block windowed compaction ----------------
__global__ __launch_bounds__(256) void proj_kernel(
    const float* __restrict__ q, const float* __restrict__ k, const float* __restrict__ v,
    const float* __restrict__ W0, const float* __restrict__ b0,
    const float* __restrict__ W1, const float* __restrict__ b1,
    const float* __restrict__ W2, const float* __restrict__ b2,
    const int* __restrict__ mask,
    short* __restrict__ Qt, short* __restrict__ Kt, short* __restrict__ Vt)
{
    __shared__ float Ws[3][DIM * DIM];
    __shared__ float bsh[3][DIM];
    __shared__ int   widx[256];
    __shared__ int   cntS;

    int tid = threadIdx.x;
    int blk = blockIdx.x;            // 3*8*4*8 = 768
    int w   = blk & 7;  blk >>= 3;   // s-window
    int h   = blk & 3;  blk >>= 2;
    int bb  = blk & 7;  blk >>= 3;
    int x   = blk;                   // 0..2
    int s0  = w * 256;

    for (int i = tid; i < DIM * DIM; i += 256) {
        Ws[0][i] = W0[i]; Ws[1][i] = W1[i]; Ws[2][i] = W2[i];
    }
    if (tid < DIM) { bsh[0][tid] = b0[tid]; bsh[1][tid] = b1[tid]; bsh[2][tid] = b2[tid]; }

    // wave 0: scan mask[bb], record gather indices for compacted window [s0,s0+256)
    if (tid < 64) {
        const int* mrow = mask + bb * SEQ;
        int base = 0;
        for (int ch = 0; ch < SEQ; ch += 64) {
            int mv = mrow[ch + tid];
            unsigned long long bal = __ballot(mv != 0);
            int pos = base + (int)__popcll(bal & ((1ull << tid) - 1ull));
            if (mv && pos >= s0 && pos < s0 + 256) widx[pos - s0] = ch + tid;
            base += (int)__popcll(bal);
        }
        if (tid == 0) cntS = base;
    }
    __syncthreads();

    int  cnt   = cntS;
    int  c     = s0 + tid;
    bool valid = c < cnt;
    int  gs    = valid ? widx[tid] : 0;

    const float QSC = 0.44721359549995793f * 1.4426950408889634f;  // (1/sqrt5)*log2(e)
    const float* base = (x == 0) ? q : ((x == 1) ? k : v);

    float xq[DIM], xg[DIM];
    {
        const float4* r4 = (const float4*)(base + (size_t)(bb * SEQ + c) * DIM);
        const float4* g4 = (const float4*)(base + (size_t)(bb * SEQ + gs) * DIM);
        #pragma unroll
        for (int i = 0; i < 5; ++i) {
            float4 a = r4[i], g = g4[i];
            xq[i*4+0]=a.x; xq[i*4+1]=a.y; xq[i*4+2]=a.z; xq[i*4+3]=a.w;
            xg[i*4+0]=g.x; xg[i*4+1]=g.y; xg[i*4+2]=g.z; xg[i*4+3]=g.w;
        }
    }

    #define DOT20(xv, t, j, dst) {                                        \
        float acc_ = bsh[t][j];                                           \
        const float4* wr_ = (const float4*)&Ws[t][(j) * DIM];             \
        _Pragma("unroll")                                                 \
        for (int i4 = 0; i4 < 5; ++i4) {                                  \
            float4 w_ = wr_[i4];                                          \
            acc_ += (xv)[i4*4+0]*w_.x + (xv)[i4*4+1]*w_.y                 \
                  + (xv)[i4*4+2]*w_.z + (xv)[i4*4+3]*w_.w;                \
        }                                                                 \
        dst = acc_;                                                       \
    }

    size_t row = ((size_t)(x * B + bb) * H + h) * SEQ + c;

    // Q-role (W0): pre-scaled, hi/lo bf16 split; hi[5]=1 (bias), lo[5]=0
    short8 qhi = {0, 0, 0, 0, 0, ONEB, 0, 0};
    short8 qlo = {0, 0, 0, 0, 0, 0, 0, 0};
    #pragma unroll
    for (int d = 0; d < DKN; ++d) {
        float y; DOT20(xq, 0, h * DKN + d, y);
        y *= QSC;
        unsigned short hb = bf16b(y);
        qhi[d] = (short)hb;
        qlo[d] = (short)bf16b(y - bf16f(hb));
    }
    ((short8*)Qt)[row * 2 + 0] = qhi;
    ((short8*)Qt)[row * 2 + 1] = qlo;

    // K-role (W1) on gathered key row, or sentinel ([5] = -28672 -> P = 0)
    short8 rk = {0, 0, 0, 0, 0, valid ? (short)0 : SENTB, 0, 0};
    if (valid) {
        #pragma unroll
        for (int d = 0; d < DKN; ++d) {
            float y; DOT20(xg, 1, h * DKN + d, y);
            rk[d] = (short)bf16b(y);
        }
    }
    ((short8*)Kt)[row] = rk;

    // V-role (W2): transposed store at sig32-permuted column; row5 = 1 (l-col)
    if (valid) {
        size_t vb = ((size_t)(x * B + bb) * H + h) * 8 * SEQ;
        int vcol = (c & ~31) + sig32(c & 31);
        #pragma unroll
        for (int d = 0; d < DKN; ++d) {
            float y; DOT20(xg, 2, h * DKN + d, y);
            Vt[vb + (size_t)d * SEQ + vcol] = (short)bf16b(y);
        }
        Vt[vb + (size_t)5 * SEQ + vcol] = ONEB;
    }
}

// ---------------- barrier-free MFMA flash attention (32x32x16 S^T form) ----------------
// 2 waves/block, each wave independent; each wave processes 2 q-tiles sequentially.
__global__ __launch_bounds__(128) void attn_kernel(
    const short* __restrict__ Qt, const short* __restrict__ Kt,
    const short* __restrict__ Vt, const int* __restrict__ mask,
    float* __restrict__ pre)
{
    int lane = threadIdx.x & 63;
    int l31  = lane & 31, half = lane >> 5;

    int lin = blockIdx.x * 2 + (threadIdx.x >> 6);   // 3072*2 = 6144 waves
    int qt  = lin & 31; lin >>= 5;
    int h   = lin & 3;  lin >>= 2;
    int b   = lin & 7;  lin >>= 3;
    int p   = lin;
    int a   = (0x212010 >> (4 * p)) & 0xF;   // Q source
    int kv  = (0x120201 >> (4 * p)) & 0xF;   // K/V source

    // derive cnt from mask (no compaction kernel): 32 coalesced ballots
    const int* mrow = mask + b * SEQ;
    int cnt = 0;
    #pragma unroll 8
    for (int c = 0; c < SEQ; c += 64)
        cnt += (int)__popcll(__ballot(mrow[c + lane] != 0));
    int kend = (cnt + 31) & ~31;

    const short*  Qb = Qt + ((size_t)(a  * B + b) * H + h) * SEQ * 16;
    const short8* Kb = (const short8*)Kt + ((size_t)(kv * B + b) * H + h) * SEQ;
    const short*  Vb = Vt + ((size_t)(kv * B + b) * H + h) * 8 * SEQ;
    const short*  Vr = Vb + (size_t)(l31 & 7) * SEQ + half * 8;

    f32x16 zc = {0.f,0.f,0.f,0.f,0.f,0.f,0.f,0.f,0.f,0.f,0.f,0.f,0.f,0.f,0.f,0.f};

    #pragma unroll
    for (int t = 0; t < 2; ++t) {
        int qbase = qt * 32 + t * 1024;
        // B-frag Q: B[n=q=l31][k=half*8+j]; half0 = Q-hi (k0-7), half1 = Q-lo (k8-15)
        short8 qf = *(const short8*)(Qb + (size_t)(qbase + l31) * 16 + half * 8);
        f32x16 acc = zc;

        for (int c0 = 0; c0 < kend; c0 += 32) {
            // A-frag K: A[m=key=l31][k=half*8+j] (same row both halves = hi/lo contract)
            short8 kf = Kb[c0 + l31];
            short8 va = *(const short8*)(Vr + c0);
            short8 vc = *(const short8*)(Vr + c0 + 16);

            // S^T: D col=q=l31, key=(reg&3)+8*(reg>>2)+4*half
            f32x16 d = __builtin_amdgcn_mfma_f32_32x32x16_bf16(kf, qf, zc, 0, 0, 0);

            // exp2 -> trunc bf16 pairs; D-reg order == PV B-frag k-slot order (sig32'd V)
            unsigned pd1[4], pd2[4];
            #pragma unroll
            for (int r = 0; r < 4; ++r) {
                pd1[r] = pk_trunc(EXP2(d[2 * r]),     EXP2(d[2 * r + 1]));
                pd2[r] = pk_trunc(EXP2(d[2 * r + 8]), EXP2(d[2 * r + 9]));
            }
            short8 pf1, pf2;
            __builtin_memcpy(&pf1, pd1, 16);
            __builtin_memcpy(&pf2, pd2, 16);

            // O^T: A=V^T[m=dim][k-slot], B=P[n=q][k-slot]; Vt row5=1 -> row5 of D = l
            acc = __builtin_amdgcn_mfma_f32_32x32x16_bf16(va, pf1, acc, 0, 0, 0);
            acc = __builtin_amdgcn_mfma_f32_32x32x16_bf16(vc, pf2, acc, 0, 0, 0);
        }

        // D rows: dim0-3 = half0 regs 0-3; dim4 = half1 reg0; l (row5) = half1 reg1
        float lv  = __shfl(acc[1], 32 + l31, 64);
        float inv = 1.0f / lv;
        float* dst = pre + (((size_t)p * B + b) * H + h) * SEQ * PRE8
                         + (size_t)(qbase + l31) * PRE8;
        if (half == 0) {
            *(float4*)dst = make_float4(acc[0]*inv, acc[1]*inv, acc[2]*inv, acc[3]*inv);
        } else {
            dst[4] = acc[0] * inv;
        }
    }
}

// ---------------- sum 6 pairs + output projection ----------------
__global__ __launch_bounds__(256) void final_kernel(
    const float* __restrict__ pre,
    const float* __restrict__ W3, const float* __restrict__ b3,
    float* __restrict__ out)
{
    __shared__ float Ws[DIM * DIM];
    __shared__ float bs[DIM];
    int tid = threadIdx.x;
    for (int i = tid; i < DIM * DIM; i += 256) Ws[i] = W3[i];
    if (tid < DIM) bs[tid] = b3[tid];
    __syncthreads();

    int g = blockIdx.x * 256 + tid;      // B*SEQ = 16384 exactly
    int b = g / SEQ;
    int s = g - b * SEQ;

    float x[DIM];
    #pragma unroll
    for (int i = 0; i < DIM; ++i) x[i] = 0.f;

    for (int p = 0; p < 6; ++p) {
        #pragma unroll
        for (int h = 0; h < H; ++h) {
            const float* sr = pre + (((size_t)p * B + b) * H + h) * SEQ * PRE8
                                  + (size_t)s * PRE8;
            float4 a = *(const float4*)sr;
            float  a4 = sr[4];
            x[h * DKN + 0] += a.x; x[h * DKN + 1] += a.y; x[h * DKN + 2] += a.z;
            x[h * DKN + 3] += a.w; x[h * DKN + 4] += a4;
        }
    }

    float y[DIM];
    for (int j = 0; j < DIM; ++j) {
        float acc = bs[j];
        const float4* wr = (const float4*)&Ws[j * DIM];
        #pragma unroll
        for (int i4 = 0; i4 < 5; ++i4) {
            float4 w = wr[i4];
            acc += x[i4*4+0]*w.x + x[i4*4+1]*w.y + x[i4*4+2]*w.z + x[i4*4+3]*w.w;
        }
        y[j] = acc;
    }
    float4* dst = (float4*)(out + (size_t)(b * SEQ + s) * DIM);
    #pragma unroll
    for (int j4 = 0; j4 < 5; ++j4)
        dst[j4] = make_float4(y[j4*4+0], y[j4*4+1], y[j4*4+2], y[j4*4+3]);
}

extern "C" void kernel_launch(void* const* d_in, const int* in_sizes, int n_in,
                              void* d_out, int out_size, void* d_ws, size_t ws_size,
                              hipStream_t stream) {
    const float* q    = (const float*)d_in[0];
    const float* k    = (const float*)d_in[1];
    const float* v    = (const float*)d_in[2];
    const int*   mask = (const int*)d_in[3];
    const float* W0 = (const float*)d_in[4];  const float* b0 = (const float*)d_in[5];
    const float* W1 = (const float*)d_in[6];  const float* b1 = (const float*)d_in[7];
    const float* W2 = (const float*)d_in[8];  const float* b2 = (const float*)d_in[9];
    const float* W3 = (const float*)d_in[10]; const float* b3 = (const float*)d_in[11];

    const size_t NROW = (size_t)3 * B * H * SEQ;       // 196608
    short* Qt = (short*)d_ws;                          // NROW*16 shorts (6 MB)
    short* Kt = Qt + NROW * 16;                        // NROW*8 shorts  (3 MB)
    short* Vt = Kt + NROW * 8;                         // NROW*8 shorts  (3 MB)
    float* pre = (float*)(Vt + NROW * 8);              // 6*B*H*SEQ*8 floats (12.6 MB)
    float* out = (float*)d_out;

    proj_kernel<<<dim3(3 * B * H * (SEQ / 256)), dim3(256), 0, stream>>>(
        q, k, v, W0, b0, W1, b1, W2, b2, mask, Qt, Kt, Vt);
    attn_kernel<<<dim3(6 * B * H * 32 / 2), dim3(128), 0, stream>>>(
        Qt, Kt, Vt, mask, pre);
    final_kernel<<<dim3(B * SEQ / 256), dim3(256), 0, stream>>>(pre, W3, b3, out);
}

// Round 10
// 174.770 us; speedup vs baseline: 1.4285x; 1.1828x over previous
//
#include <hip/hip_runtime.h>
#include <cstdint>
#include <cstddef>

#define B    8
#define SEQ  2048
#define H    4
#define DKN  5
#define DIM  20
#define PRE8 8
#define SENTB ((short)0xC6E0) // bf16(-28672): exp2(score-28672) == 0
#define ONEB  ((short)0x3F80) // bf16(1.0)

typedef short short8 __attribute__((ext_vector_type(8)));
typedef float f32x16 __attribute__((ext_vector_type(16)));

#if __has_builtin(__builtin_amdgcn_exp2f)
#define EXP2(x) __builtin_amdgcn_exp2f(x)
#else
#define EXP2(x) __expf((x) * 0.6931471805599453f)
#endif

static __device__ __forceinline__ unsigned short bf16b(float x) {
    union { float f; unsigned u; } v; v.f = x;
    unsigned r = v.u + 0x7FFFu + ((v.u >> 16) & 1u);   // RTNE
    return (unsigned short)(r >> 16);
}
static __device__ __forceinline__ float bf16f(unsigned short h) {
    union { unsigned u; float f; } v; v.u = ((unsigned)h) << 16;
    return v.f;
}
// one-instruction truncating bf16 pack: D = {hi16(y), hi16(x)} via v_perm_b32
static __device__ __forceinline__ unsigned pk_trunc(float x, float y) {
    union { float f; unsigned u; } a, b; a.f = x; b.f = y;
    return __builtin_amdgcn_perm(b.u, a.u, 0x07060302u);
}
// key offset t (0..31) -> Vt physical column slot (32x32x16 PV k-slot inverse)
static __device__ __forceinline__ int sig32(int t) {
    return (t & 19) | ((t & 4) << 1) | ((t & 8) >> 1);
}

// ws layout:
//   Qt : short [x][b][h][s][16]   hi(0..7, [5]=1 bias) | lo(8..15, [5]=0)   6 MB
//   Kt : short [x][b][h][c][8]    compacted keys; c>=cnt sentinel           3 MB
//   Vt : short [x][b][h][8][SEQ]  transposed values at sig32 columns; r5=1  3 MB
//   pre : float [p][b][h][s][8]                                            12.6 MB
//   meta: int [B]

// ---------------- projections + in-block windowed compaction ----------------
__global__ __launch_bounds__(256) void proj_kernel(
    const float* __restrict__ q, const float* __restrict__ k, const float* __restrict__ v,
    const float* __restrict__ W0, const float* __restrict__ b0,
    const float* __restrict__ W1, const float* __restrict__ b1,
    const float* __restrict__ W2, const float* __restrict__ b2,
    const int* __restrict__ mask,
    short* __restrict__ Qt, short* __restrict__ Kt, short* __restrict__ Vt,
    int* __restrict__ meta)
{
    __shared__ float Ws[3][DIM * DIM];
    __shared__ float bsh[3][DIM];
    __shared__ int   widx[256];
    __shared__ int   cntS;

    int tid = threadIdx.x;
    int blk = blockIdx.x;            // 3*8*4*8 = 768
    int w   = blk & 7;  blk >>= 3;   // s-window
    int h   = blk & 3;  blk >>= 2;
    int bb  = blk & 7;  blk >>= 3;
    int x   = blk;                   // 0..2
    int s0  = w * 256;

    for (int i = tid; i < DIM * DIM; i += 256) {
        Ws[0][i] = W0[i]; Ws[1][i] = W1[i]; Ws[2][i] = W2[i];
    }
    if (tid < DIM) { bsh[0][tid] = b0[tid]; bsh[1][tid] = b1[tid]; bsh[2][tid] = b2[tid]; }

    // wave 0: scan mask[bb], record gather indices for compacted window [s0,s0+256)
    if (tid < 64) {
        const int* mrow = mask + bb * SEQ;
        int base = 0;
        for (int ch = 0; ch < SEQ; ch += 64) {
            int mv = mrow[ch + tid];
            unsigned long long bal = __ballot(mv != 0);
            int pos = base + (int)__popcll(bal & ((1ull << tid) - 1ull));
            if (mv && pos >= s0 && pos < s0 + 256) widx[pos - s0] = ch + tid;
            base += (int)__popcll(bal);
        }
        if (tid == 0) {
            cntS = base;
            if (x == 0 && h == 0 && w == 0) meta[bb] = base;
        }
    }
    __syncthreads();

    int  cnt   = cntS;
    int  c     = s0 + tid;
    bool valid = c < cnt;
    int  gs    = valid ? widx[tid] : 0;

    const float QSC = 0.44721359549995793f * 1.4426950408889634f;  // (1/sqrt5)*log2(e)
    const float* base = (x == 0) ? q : ((x == 1) ? k : v);

    float xq[DIM], xg[DIM];
    {
        const float4* r4 = (const float4*)(base + (size_t)(bb * SEQ + c) * DIM);
        const float4* g4 = (const float4*)(base + (size_t)(bb * SEQ + gs) * DIM);
        #pragma unroll
        for (int i = 0; i < 5; ++i) {
            float4 a = r4[i], g = g4[i];
            xq[i*4+0]=a.x; xq[i*4+1]=a.y; xq[i*4+2]=a.z; xq[i*4+3]=a.w;
            xg[i*4+0]=g.x; xg[i*4+1]=g.y; xg[i*4+2]=g.z; xg[i*4+3]=g.w;
        }
    }

    #define DOT20(xv, t, j, dst) {                                        \
        float acc_ = bsh[t][j];                                           \
        const float4* wr_ = (const float4*)&Ws[t][(j) * DIM];             \
        _Pragma("unroll")                                                 \
        for (int i4 = 0; i4 < 5; ++i4) {                                  \
            float4 w_ = wr_[i4];                                          \
            acc_ += (xv)[i4*4+0]*w_.x + (xv)[i4*4+1]*w_.y                 \
                  + (xv)[i4*4+2]*w_.z + (xv)[i4*4+3]*w_.w;                \
        }                                                                 \
        dst = acc_;                                                       \
    }

    size_t row = ((size_t)(x * B + bb) * H + h) * SEQ + c;

    // Q-role (W0): pre-scaled, hi/lo bf16 split; hi[5]=1 (bias), lo[5]=0
    short8 qhi = {0, 0, 0, 0, 0, ONEB, 0, 0};
    short8 qlo = {0, 0, 0, 0, 0, 0, 0, 0};
    #pragma unroll
    for (int d = 0; d < DKN; ++d) {
        float y; DOT20(xq, 0, h * DKN + d, y);
        y *= QSC;
        unsigned short hb = bf16b(y);
        qhi[d] = (short)hb;
        qlo[d] = (short)bf16b(y - bf16f(hb));
    }
    ((short8*)Qt)[row * 2 + 0] = qhi;
    ((short8*)Qt)[row * 2 + 1] = qlo;

    // K-role (W1) on gathered key row, or sentinel ([5] = -28672 -> P = 0)
    short8 rk = {0, 0, 0, 0, 0, valid ? (short)0 : SENTB, 0, 0};
    if (valid) {
        #pragma unroll
        for (int d = 0; d < DKN; ++d) {
            float y; DOT20(xg, 1, h * DKN + d, y);
            rk[d] = (short)bf16b(y);
        }
    }
    ((short8*)Kt)[row] = rk;

    // V-role (W2): transposed store at sig32-permuted column; row5 = 1 (l-col)
    if (valid) {
        size_t vb = ((size_t)(x * B + bb) * H + h) * 8 * SEQ;
        int vcol = (c & ~31) + sig32(c & 31);
        #pragma unroll
        for (int d = 0; d < DKN; ++d) {
            float y; DOT20(xg, 2, h * DKN + d, y);
            Vt[vb + (size_t)d * SEQ + vcol] = (short)bf16b(y);
        }
        Vt[vb + (size_t)5 * SEQ + vcol] = ONEB;
    }
}

// ---------------- barrier-free MFMA flash attention (32x32x16 S^T form) ----------------
// 2 waves/block; each wave processes 2 q-tiles INTERLEAVED in one shared k-loop.
__global__ __launch_bounds__(128) void attn_kernel(
    const short* __restrict__ Qt, const short* __restrict__ Kt,
    const short* __restrict__ Vt, const int* __restrict__ meta,
    float* __restrict__ pre)
{
    int lane = threadIdx.x & 63;
    int l31  = lane & 31, half = lane >> 5;

    int lin = blockIdx.x * 2 + (threadIdx.x >> 6);   // 3072*2 = 6144 waves
    int qt  = lin & 31; lin >>= 5;
    int h   = lin & 3;  lin >>= 2;
    int b   = lin & 7;  lin >>= 3;
    int p   = lin;
    int a   = (0x212010 >> (4 * p)) & 0xF;   // Q source
    int kv  = (0x120201 >> (4 * p)) & 0xF;   // K/V source

    int cnt  = meta[b];
    int kend = (cnt + 31) & ~31;

    const short*  Qb = Qt + ((size_t)(a  * B + b) * H + h) * SEQ * 16;
    const short8* Kb = (const short8*)Kt + ((size_t)(kv * B + b) * H + h) * SEQ;
    const short*  Vb = Vt + ((size_t)(kv * B + b) * H + h) * 8 * SEQ;
    const short*  Vr = Vb + (size_t)(l31 & 7) * SEQ + half * 8;

    int qb0 = qt * 32, qb1 = qt * 32 + 1024;
    // B-frag Q: B[n=q=l31][k=half*8+j]; half0 = Q-hi (k0-7), half1 = Q-lo (k8-15)
    short8 qf0 = *(const short8*)(Qb + (size_t)(qb0 + l31) * 16 + half * 8);
    short8 qf1 = *(const short8*)(Qb + (size_t)(qb1 + l31) * 16 + half * 8);

    f32x16 zc = {0.f,0.f,0.f,0.f,0.f,0.f,0.f,0.f,0.f,0.f,0.f,0.f,0.f,0.f,0.f,0.f};
    f32x16 acc0 = zc, acc1 = zc;

    // prefetch iteration 0
    short8 kf = Kb[l31];
    short8 va = *(const short8*)(Vr);
    short8 vc = *(const short8*)(Vr + 16);

    for (int c0 = 0; c0 < kend; c0 += 32) {
        int c1 = c0 + 32;   // last prefetch reads stray in-ws bytes, never consumed
        short8 kf_n = Kb[c1 + l31];
        short8 va_n = *(const short8*)(Vr + c1);
        short8 vc_n = *(const short8*)(Vr + c1 + 16);

        // S^T: D col=q=l31, key=(reg&3)+8*(reg>>2)+4*half — two independent q-tiles
        f32x16 d0 = __builtin_amdgcn_mfma_f32_32x32x16_bf16(kf, qf0, zc, 0, 0, 0);
        f32x16 d1 = __builtin_amdgcn_mfma_f32_32x32x16_bf16(kf, qf1, zc, 0, 0, 0);

        // exp2 -> trunc bf16 pairs; D-reg order == PV B-frag k-slot order (sig32'd V)
        unsigned pA0[4], pA1[4], pB0[4], pB1[4];
        #pragma unroll
        for (int r = 0; r < 4; ++r) {
            pA0[r] = pk_trunc(EXP2(d0[2 * r]),     EXP2(d0[2 * r + 1]));
            pA1[r] = pk_trunc(EXP2(d0[2 * r + 8]), EXP2(d0[2 * r + 9]));
            pB0[r] = pk_trunc(EXP2(d1[2 * r]),     EXP2(d1[2 * r + 1]));
            pB1[r] = pk_trunc(EXP2(d1[2 * r + 8]), EXP2(d1[2 * r + 9]));
        }
        short8 fA0, fA1, fB0, fB1;
        __builtin_memcpy(&fA0, pA0, 16);  __builtin_memcpy(&fA1, pA1, 16);
        __builtin_memcpy(&fB0, pB0, 16);  __builtin_memcpy(&fB1, pB1, 16);

        // O^T: A=V^T[m=dim][k-slot], B=P[n=q][k-slot]; Vt row5=1 -> row5 of D = l
        acc0 = __builtin_amdgcn_mfma_f32_32x32x16_bf16(va, fA0, acc0, 0, 0, 0);
        acc1 = __builtin_amdgcn_mfma_f32_32x32x16_bf16(va, fB0, acc1, 0, 0, 0);
        acc0 = __builtin_amdgcn_mfma_f32_32x32x16_bf16(vc, fA1, acc0, 0, 0, 0);
        acc1 = __builtin_amdgcn_mfma_f32_32x32x16_bf16(vc, fB1, acc1, 0, 0, 0);

        kf = kf_n; va = va_n; vc = vc_n;
    }

    // D rows: dim0-3 = half0 regs 0-3; dim4 = half1 reg0; l (row5) = half1 reg1
    float* base0 = pre + (((size_t)p * B + b) * H + h) * SEQ * PRE8;
    {
        float lv  = __shfl(acc0[1], 32 + l31, 64);
        float inv = 1.0f / lv;
        float* dst = base0 + (size_t)(qb0 + l31) * PRE8;
        if (half == 0)
            *(float4*)dst = make_float4(acc0[0]*inv, acc0[1]*inv, acc0[2]*inv, acc0[3]*inv);
        else
            dst[4] = acc0[0] * inv;
    }
    {
        float lv  = __shfl(acc1[1], 32 + l31, 64);
        float inv = 1.0f / lv;
        float* dst = base0 + (size_t)(qb1 + l31) * PRE8;
        if (half == 0)
            *(float4*)dst = make_float4(acc1[0]*inv, acc1[1]*inv, acc1[2]*inv, acc1[3]*inv);
        else
            dst[4] = acc1[0] * inv;
    }
}

// ---------------- sum 6 pairs + output projection ----------------
__global__ __launch_bounds__(256) void final_kernel(
    const float* __restrict__ pre,
    const float* __restrict__ W3, const float* __restrict__ b3,
    float* __restrict__ out)
{
    __shared__ float Ws[DIM * DIM];
    __shared__ float bs[DIM];
    int tid = threadIdx.x;
    for (int i = tid; i < DIM * DIM; i += 256) Ws[i] = W3[i];
    if (tid < DIM) bs[tid] = b3[tid];
    __syncthreads();

    int g = blockIdx.x * 256 + tid;      // B*SEQ = 16384 exactly
    int b = g / SEQ;
    int s = g - b * SEQ;

    float x[DIM];
    #pragma unroll
    for (int i = 0; i < DIM; ++i) x[i] = 0.f;

    for (int p = 0; p < 6; ++p) {
        #pragma unroll
        for (int h = 0; h < H; ++h) {
            const float* sr = pre + (((size_t)p * B + b) * H + h) * SEQ * PRE8
                                  + (size_t)s * PRE8;
            float4 a = *(const float4*)sr;
            float  a4 = sr[4];
            x[h * DKN + 0] += a.x; x[h * DKN + 1] += a.y; x[h * DKN + 2] += a.z;
            x[h * DKN + 3] += a.w; x[h * DKN + 4] += a4;
        }
    }

    float y[DIM];
    for (int j = 0; j < DIM; ++j) {
        float acc = bs[j];
        const float4* wr = (const float4*)&Ws[j * DIM];
        #pragma unroll
        for (int i4 = 0; i4 < 5; ++i4) {
            float4 w = wr[i4];
            acc += x[i4*4+0]*w.x + x[i4*4+1]*w.y + x[i4*4+2]*w.z + x[i4*4+3]*w.w;
        }
        y[j] = acc;
    }
    float4* dst = (float4*)(out + (size_t)(b * SEQ + s) * DIM);
    #pragma unroll
    for (int j4 = 0; j4 < 5; ++j4)
        dst[j4] = make_float4(y[j4*4+0], y[j4*4+1], y[j4*4+2], y[j4*4+3]);
}

extern "C" void kernel_launch(void* const* d_in, const int* in_sizes, int n_in,
                              void* d_out, int out_size, void* d_ws, size_t ws_size,
                              hipStream_t stream) {
    const float* q    = (const float*)d_in[0];
    const float* k    = (const float*)d_in[1];
    const float* v    = (const float*)d_in[2];
    const int*   mask = (const int*)d_in[3];
    const float* W0 = (const float*)d_in[4];  const float* b0 = (const float*)d_in[5];
    const float* W1 = (const float*)d_in[6];  const float* b1 = (const float*)d_in[7];
    const float* W2 = (const float*)d_in[8];  const float* b2 = (const float*)d_in[9];
    const float* W3 = (const float*)d_in[10]; const float* b3 = (const float*)d_in[11];

    const size_t NROW = (size_t)3 * B * H * SEQ;       // 196608
    short* Qt = (short*)d_ws;                          // NROW*16 shorts (6 MB)
    short* Kt = Qt + NROW * 16;                        // NROW*8 shorts  (3 MB)
    short* Vt = Kt + NROW * 8;                         // NROW*8 shorts  (3 MB)
    float* pre = (float*)(Vt + NROW * 8);              // 6*B*H*SEQ*8 floats (12.6 MB)
    int*   meta = (int*)(pre + (size_t)6 * B * H * SEQ * PRE8);
    float* out = (float*)d_out;

    proj_kernel<<<dim3(3 * B * H * (SEQ / 256)), dim3(256), 0, stream>>>(
        q, k, v, W0, b0, W1, b1, W2, b2, mask, Qt, Kt, Vt, meta);
    attn_kernel<<<dim3(6 * B * H * 32 / 2), dim3(128), 0, stream>>>(
        Qt, Kt, Vt, meta, pre);
    final_kernel<<<dim3(B * SEQ / 256), dim3(256), 0, stream>>>(pre, W3, b3, out);
}